// Round 1
// baseline (8310.386 us; speedup 1.0000x reference)
//
#include <hip/hip_runtime.h>
#include <hip/hip_bf16.h>
#include <cstdint>
#include <cstddef>

typedef unsigned short u16;
typedef __attribute__((ext_vector_type(8))) __bf16 bf16x8;
typedef __attribute__((ext_vector_type(4))) float f32x4;

#define B_   128
#define T_   256
#define E_   512
#define H_   1024
#define G4_  4096
#define K_   1536
#define F_   512
#define O_   10

__device__ __forceinline__ u16 f2bf(float f) {
  unsigned int u = __float_as_uint(f);
  u += 0x7FFFu + ((u >> 16) & 1u);
  return (u16)(u >> 16);
}
__device__ __forceinline__ float bf2f(u16 h) {
  return __uint_as_float(((unsigned int)h) << 16);
}

// ---------------------------------------------------------------- build xe16
// xe16[b*T+t][e] = bf16(emb[x[b][t]][e]);  32768 rows x 512
__global__ void build_xe(const int* __restrict__ x, const float* __restrict__ emb,
                         u16* __restrict__ xe16) {
  int id = blockIdx.x * 256 + threadIdx.x;   // over 32768*128 float4-groups
  int row = id >> 7;
  int c = (id & 127) << 2;
  int v = x[row];
  const float4 f = *(const float4*)&emb[(size_t)v * E_ + c];
  ushort4 o;
  o.x = f2bf(f.x); o.y = f2bf(f.y); o.z = f2bf(f.z); o.w = f2bf(f.w);
  *(ushort4*)&xe16[(size_t)row * E_ + c] = o;
}

// ---------------------------------------------------------------- weights
// W16[g][0:512]=w_ih[g], W16[g][512:1536]=w_hh[g]   (bf16)
__global__ void convert_w(const float* __restrict__ w_ih, const float* __restrict__ w_hh,
                          u16* __restrict__ W16) {
  int id = blockIdx.x * 256 + threadIdx.x;   // over 4096*384 float4-groups
  int g = id / 384;
  int c = (id - g * 384) << 2;
  float4 f;
  if (c < E_) f = *(const float4*)&w_ih[(size_t)g * E_ + c];
  else        f = *(const float4*)&w_hh[(size_t)g * H_ + (c - E_)];
  ushort4 o;
  o.x = f2bf(f.x); o.y = f2bf(f.y); o.z = f2bf(f.z); o.w = f2bf(f.w);
  *(ushort4*)&W16[(size_t)g * K_ + c] = o;
}

// ---------------------------------------------------------------- topic bias
// tb[m][g] = b[g] + sum_k x_top[m][k] * w_th[g][k]   (fp32, time-invariant)
__global__ void topicb(const float* __restrict__ x_top, const float* __restrict__ w_th,
                       const float* __restrict__ bias, float* __restrict__ tb) {
  int m = blockIdx.x;
  __shared__ float xt[128];
  if (threadIdx.x < 128) xt[threadIdx.x] = x_top[m * 128 + threadIdx.x];
  __syncthreads();
  for (int g = threadIdx.x; g < G4_; g += 256) {
    const float* wr = &w_th[(size_t)g * 128];
    float s = bias[g];
#pragma unroll 8
    for (int k = 0; k < 128; ++k) s += xt[k] * wr[k];
    tb[(size_t)m * G4_ + g] = s;
  }
}

// ---------------------------------------------------------------- LSTM step
// block j owns h-cols [8j,8j+8); gate cols for local col lc in [0,32):
//   g(lc) = (lc>>3)*1024 + 8j + (lc&7)    (gates 0..3 = i,f,g,o)
// gates[m][g] = tb[m][g] + sum_k in[m][k]*W16[g][k],  in = [xe_t | hx]
// MFMA 16x16x32 bf16, fragments loaded direct from global (no LDS).
__global__ __launch_bounds__(256) void lstm_step(
    int t, const u16* __restrict__ xe16, const u16* __restrict__ hx_in,
    u16* __restrict__ hx_out, float* __restrict__ cx,
    const u16* __restrict__ W16, const float* __restrict__ tb) {
  const int j = blockIdx.x;
  const int tid = threadIdx.x;
  const int w = tid >> 6;
  const int l = tid & 63;
  const int r = l & 15;    // A-row / B-col lane position
  const int q = l >> 4;    // k-quarter (8 elems each)

  f32x4 acc[2][2] = {};

  const int m0 = w * 32 + r;          // m-frag 0 row
  const int m1 = m0 + 16;             // m-frag 1 row
  const int g0 = (r >> 3) * H_ + j * 8 + (r & 7);        // n-frag 0 gate col
  const int g1 = (2 + (r >> 3)) * H_ + j * 8 + (r & 7);  // n-frag 1 gate col

  const u16* pa0 = xe16 + ((size_t)m0 * T_ + t) * E_ + q * 8;
  const u16* pa1 = xe16 + ((size_t)m1 * T_ + t) * E_ + q * 8;
  const u16* pb0 = W16 + (size_t)g0 * K_ + q * 8;
  const u16* pb1 = W16 + (size_t)g1 * K_ + q * 8;

  // K part 1: xe (k = 0..511)
#pragma unroll 4
  for (int it = 0; it < 16; ++it) {
    bf16x8 a0 = *(const bf16x8*)pa0; pa0 += 32;
    bf16x8 a1 = *(const bf16x8*)pa1; pa1 += 32;
    bf16x8 b0 = *(const bf16x8*)pb0; pb0 += 32;
    bf16x8 b1 = *(const bf16x8*)pb1; pb1 += 32;
    acc[0][0] = __builtin_amdgcn_mfma_f32_16x16x32_bf16(a0, b0, acc[0][0], 0, 0, 0);
    acc[0][1] = __builtin_amdgcn_mfma_f32_16x16x32_bf16(a0, b1, acc[0][1], 0, 0, 0);
    acc[1][0] = __builtin_amdgcn_mfma_f32_16x16x32_bf16(a1, b0, acc[1][0], 0, 0, 0);
    acc[1][1] = __builtin_amdgcn_mfma_f32_16x16x32_bf16(a1, b1, acc[1][1], 0, 0, 0);
  }
  // K part 2: hx (k = 512..1535), W16 pointers continue
  const u16* ph0 = hx_in + (size_t)m0 * H_ + q * 8;
  const u16* ph1 = hx_in + (size_t)m1 * H_ + q * 8;
#pragma unroll 4
  for (int it = 0; it < 32; ++it) {
    bf16x8 a0 = *(const bf16x8*)ph0; ph0 += 32;
    bf16x8 a1 = *(const bf16x8*)ph1; ph1 += 32;
    bf16x8 b0 = *(const bf16x8*)pb0; pb0 += 32;
    bf16x8 b1 = *(const bf16x8*)pb1; pb1 += 32;
    acc[0][0] = __builtin_amdgcn_mfma_f32_16x16x32_bf16(a0, b0, acc[0][0], 0, 0, 0);
    acc[0][1] = __builtin_amdgcn_mfma_f32_16x16x32_bf16(a0, b1, acc[0][1], 0, 0, 0);
    acc[1][0] = __builtin_amdgcn_mfma_f32_16x16x32_bf16(a1, b0, acc[1][0], 0, 0, 0);
    acc[1][1] = __builtin_amdgcn_mfma_f32_16x16x32_bf16(a1, b1, acc[1][1], 0, 0, 0);
  }

  // epilogue: D col = lane&15 -> local col; row = q*4 + reg
  // ni=0: lanes 0-7 hold i, 8-15 hold f; ni=1: g / o.  Pair via shfl_xor(8).
  const int hcg = j * 8 + (r & 7);
  const bool lower = (r & 8) == 0;
#pragma unroll
  for (int mi = 0; mi < 2; ++mi) {
#pragma unroll
    for (int rr = 0; rr < 4; ++rr) {
      const int m = w * 32 + mi * 16 + q * 4 + rr;
      float v0 = acc[mi][0][rr] + tb[(size_t)m * G4_ + g0];
      float v1 = acc[mi][1][rr] + tb[(size_t)m * G4_ + g1];
      float p0 = __shfl_xor(v0, 8);
      float p1 = __shfl_xor(v1, 8);
      float iv = lower ? v0 : p0;
      float fv = lower ? p0 : v0;
      float gv = lower ? v1 : p1;
      float ov = lower ? p1 : v1;
      iv = 1.f / (1.f + __expf(-iv));
      fv = 1.f / (1.f + __expf(-fv));
      ov = 1.f / (1.f + __expf(-ov));
      gv = tanhf(gv);
      float cn = fv * cx[(size_t)m * H_ + hcg] + iv * gv;
      float hn = ov * tanhf(cn);
      if (lower) {
        cx[(size_t)m * H_ + hcg] = cn;
        hx_out[(size_t)m * H_ + hcg] = f2bf(hn);
      }
    }
  }
}

// ---------------------------------------------------------------- fc1 + BN
// one block per feature f (512 blocks, 128 threads = one per batch row)
__global__ void fc1_bn(const u16* __restrict__ hxf, const float* __restrict__ w,
                       const float* __restrict__ bvec, const float* __restrict__ gamma,
                       const float* __restrict__ beta, float* __restrict__ h1n) {
  const int f = blockIdx.x;
  const int m = threadIdx.x;
  __shared__ float wrow[H_];
  __shared__ float red[128];
  for (int k = m; k < H_; k += 128) wrow[k] = w[(size_t)f * H_ + k];
  __syncthreads();
  float s = bvec[f];
  const u16* hr = &hxf[(size_t)m * H_];
  for (int k = 0; k < H_; k += 4) {
    ushort4 h4 = *(const ushort4*)&hr[k];
    s += bf2f(h4.x) * wrow[k] + bf2f(h4.y) * wrow[k + 1] +
         bf2f(h4.z) * wrow[k + 2] + bf2f(h4.w) * wrow[k + 3];
  }
  red[m] = s;
  __syncthreads();
  for (int off = 64; off > 0; off >>= 1) {
    if (m < off) red[m] += red[m + off];
    __syncthreads();
  }
  float mu = red[0] * (1.f / 128.f);
  __syncthreads();
  float d = s - mu;
  red[m] = d * d;
  __syncthreads();
  for (int off = 64; off > 0; off >>= 1) {
    if (m < off) red[m] += red[m + off];
    __syncthreads();
  }
  float var = red[0] * (1.f / 128.f);
  h1n[(size_t)m * F_ + f] = d * rsqrtf(var + 1e-5f) * gamma[f] + beta[f];
}

// ---------------------------------------------------------------- fc2
__global__ void fc2k(const float* __restrict__ h1n, const float* __restrict__ w,
                     const float* __restrict__ bvec, float* __restrict__ out) {
  int id = blockIdx.x * 256 + threadIdx.x;   // 1280 total
  if (id >= B_ * O_) return;
  int m = id / O_;
  int o = id - m * O_;
  float s = bvec[o];
  const float* hr = &h1n[(size_t)m * F_];
  const float* wr = &w[(size_t)o * F_];
#pragma unroll 8
  for (int k = 0; k < F_; ++k) s += hr[k] * wr[k];
  out[(size_t)m * O_ + o] = s;
}

// ---------------------------------------------------------------- launch
extern "C" void kernel_launch(void* const* d_in, const int* in_sizes, int n_in,
                              void* d_out, int out_size, void* d_ws, size_t ws_size,
                              hipStream_t stream) {
  const int*   x     = (const int*)  d_in[0];
  const float* x_top = (const float*)d_in[1];
  const float* emb   = (const float*)d_in[2];
  const float* w_ih  = (const float*)d_in[3];
  const float* w_hh  = (const float*)d_in[4];
  const float* w_th  = (const float*)d_in[5];
  const float* bvec  = (const float*)d_in[6];
  const float* fc1_w = (const float*)d_in[7];
  const float* fc1_b = (const float*)d_in[8];
  const float* gamma = (const float*)d_in[9];
  const float* beta  = (const float*)d_in[10];
  const float* fc2_w = (const float*)d_in[11];
  const float* fc2_b = (const float*)d_in[12];
  float* out = (float*)d_out;

  // ws layout (bytes)
  const size_t OFF_XE  = 0;          // 33,554,432  xe16 [B*T][E] bf16
  const size_t OFF_W   = 33554432;   // 12,582,912  W16  [4H][K] bf16
  const size_t OFF_TB  = 46137344;   //  2,097,152  tb   [B][4H] f32
  const size_t OFF_HX0 = 48234496;   //    262,144  hx ping  bf16
  const size_t OFF_HX1 = 48496640;   //    262,144  hx pong  bf16
  const size_t OFF_CX  = 48758784;   //    524,288  cx  [B][H] f32
  const size_t OFF_H1  = 49283072;   //    262,144  h1n [B][F] f32
  const size_t NEED    = 49545216;
  if (!d_ws || ws_size < NEED) return;

  char* ws = (char*)d_ws;
  u16*   xe16 = (u16*)(ws + OFF_XE);
  u16*   W16  = (u16*)(ws + OFF_W);
  float* tb   = (float*)(ws + OFF_TB);
  u16*   hx0  = (u16*)(ws + OFF_HX0);
  u16*   hx1  = (u16*)(ws + OFF_HX1);
  float* cx   = (float*)(ws + OFF_CX);
  float* h1n  = (float*)(ws + OFF_H1);

  // zero hx0, hx1, cx (contiguous 1 MiB)
  hipMemsetAsync(ws + OFF_HX0, 0, 262144 * 2 + 524288, stream);

  build_xe<<<16384, 256, 0, stream>>>(x, emb, xe16);
  convert_w<<<6144, 256, 0, stream>>>(w_ih, w_hh, W16);
  topicb<<<128, 256, 0, stream>>>(x_top, w_th, bvec, tb);

  for (int t = 0; t < T_; ++t) {
    const u16* hin = (t & 1) ? hx1 : hx0;
    u16*       hout = (t & 1) ? hx0 : hx1;
    lstm_step<<<128, 256, 0, stream>>>(t, xe16, hin, hout, cx, W16, tb);
  }
  // T_=256 even -> final hx is in hx0

  fc1_bn<<<F_, 128, 0, stream>>>(hx0, fc1_w, fc1_b, gamma, beta, h1n);
  fc2k<<<5, 256, 0, stream>>>(h1n, fc2_w, fc2_b, out);
}